// Round 1
// baseline (180.032 us; speedup 1.0000x reference)
//
#include <hip/hip_runtime.h>
#include <stdint.h>

#define N_CLS 8192
#define FEAT  512
#define BATCH 1024
#define TILE  128
#define NTILE (N_CLS / TILE)               // 64
#define NBLK  (NTILE * (NTILE + 1) / 2)    // 2080

typedef __attribute__((ext_vector_type(8))) short short8;
typedef __attribute__((ext_vector_type(4))) float f32x4;

__device__ inline unsigned short f2bf(float x) {
    union { float f; unsigned int u; } v; v.f = x;
    unsigned int u = v.u;
    u += 0x7fffu + ((u >> 16) & 1u);       // RNE to bf16
    return (unsigned short)(u >> 16);
}
__device__ inline float bf2f(unsigned short h) {
    union { unsigned int u; float f; } v; v.u = ((unsigned int)h) << 16;
    return v.f;
}

// ---------------- Kernel 1: sequential EMA per label + bf16 hi/lo split ----
// One wave (64 threads) per class row. Each class's updates are applied in
// batch order; distinct classes are independent (matches lax.scan semantics).
__global__ __launch_bounds__(64) void ema_split_kernel(
    const float* __restrict__ features, const int* __restrict__ labels,
    const float* __restrict__ protos,
    unsigned short* __restrict__ Phi, unsigned short* __restrict__ Plo) {
    const int row  = blockIdx.x;
    const int lane = threadIdx.x;          // 0..63
    float p[8];
    #pragma unroll
    for (int j = 0; j < 8; ++j) p[j] = protos[(size_t)row * FEAT + j * 64 + lane];

    for (int c = 0; c < BATCH / 64; ++c) {
        int lab = labels[c * 64 + lane];
        unsigned long long m = __ballot(lab == row);
        while (m) {
            int b = __builtin_ctzll(m);    // lowest set bit -> earliest sample
            m &= m - 1;
            int s = c * 64 + b;
            float ss = 0.f;
            #pragma unroll
            for (int j = 0; j < 8; ++j) {
                float f = features[(size_t)s * FEAT + j * 64 + lane];
                p[j] = p[j] * 0.95f + f * 0.05f;
                ss += p[j] * p[j];
            }
            #pragma unroll
            for (int off = 32; off; off >>= 1) ss += __shfl_xor(ss, off);
            float inv = 1.0f / fmaxf(sqrtf(ss), 1e-12f);
            #pragma unroll
            for (int j = 0; j < 8; ++j) p[j] *= inv;
        }
    }
    #pragma unroll
    for (int j = 0; j < 8; ++j) {
        unsigned short hi = f2bf(p[j]);
        float lo = p[j] - bf2f(hi);
        Phi[(size_t)row * FEAT + j * 64 + lane] = hi;
        Plo[(size_t)row * FEAT + j * 64 + lane] = f2bf(lo);
    }
}

// ---------------- Kernel 2: symmetric Gram tiles + fused exp row/col sums --
// bf16x3: S = Hi*Hi^T + Hi*Lo^T + Lo*Hi^T. Upper-triangular tile pairs only.
__global__ __launch_bounds__(256) void gemm_disp_kernel(
    const unsigned short* __restrict__ Phi, const unsigned short* __restrict__ Plo,
    float* __restrict__ rowsum) {
    // 4 tiles of [128][32] bf16: 0=Ahi 1=Alo 2=Bhi 3=Blo  (32 KiB)
    __shared__ short smem[4 * TILE * 32];

    int t = blockIdx.x, I = 0;
    while (t >= NTILE - I) { t -= NTILE - I; ++I; }
    const int J = I + t;                   // J >= I

    const int wid  = threadIdx.x >> 6;     // wave 0..3
    const int lane = threadIdx.x & 63;
    const int wr = wid >> 1, wc = wid & 1; // 2x2 waves over 128x128
    const int h = lane >> 4;               // 0..3 (k-group)
    const int r = lane & 15;               // fragment row/col index

    f32x4 acc[4][4];
    #pragma unroll
    for (int m = 0; m < 4; ++m)
        #pragma unroll
        for (int n = 0; n < 4; ++n) acc[m][n] = (f32x4){0.f, 0.f, 0.f, 0.f};

    // staging: wave `wid` stages tile `wid` (8 chunks of 16 rows = 1 KiB each)
    const unsigned short* sbase = (wid & 1) ? Plo : Phi;
    const int grow0 = ((wid < 2) ? I : J) * TILE;
    const int srow = lane >> 2;            // row within 16-row chunk
    const int sseg = lane & 3;             // 16B segment within 64B row

    for (int ks = 0; ks < 16; ++ks) {
        const int kk = ks * 32;
        #pragma unroll
        for (int c = 0; c < 8; ++c) {
            const unsigned short* gsrc =
                sbase + (size_t)(grow0 + c * 16 + srow) * FEAT + kk + sseg * 8;
            short* ldst = smem + wid * 4096 + c * 512;   // wave-uniform base
            __builtin_amdgcn_global_load_lds(
                (const __attribute__((address_space(1))) void*)gsrc,
                (__attribute__((address_space(3))) void*)ldst, 16, 0, 0);
        }
        __syncthreads();

        short8 ahi[4], alo[4], bhi[4], blo[4];
        #pragma unroll
        for (int m = 0; m < 4; ++m) {
            int arow = wr * 64 + m * 16 + r;
            int brow = wc * 64 + m * 16 + r;
            ahi[m] = *(const short8*)(smem + 0 * 4096 + arow * 32 + h * 8);
            alo[m] = *(const short8*)(smem + 1 * 4096 + arow * 32 + h * 8);
            bhi[m] = *(const short8*)(smem + 2 * 4096 + brow * 32 + h * 8);
            blo[m] = *(const short8*)(smem + 3 * 4096 + brow * 32 + h * 8);
        }
        #pragma unroll
        for (int m = 0; m < 4; ++m)
            #pragma unroll
            for (int n = 0; n < 4; ++n) {
                acc[m][n] = __builtin_amdgcn_mfma_f32_16x16x32_bf16(ahi[m], bhi[n], acc[m][n], 0, 0, 0);
                acc[m][n] = __builtin_amdgcn_mfma_f32_16x16x32_bf16(ahi[m], blo[n], acc[m][n], 0, 0, 0);
                acc[m][n] = __builtin_amdgcn_mfma_f32_16x16x32_bf16(alo[m], bhi[n], acc[m][n], 0, 0, 0);
            }
        __syncthreads();
    }

    // epilogue: e = exp(10*S), zero diagonal, reduce row/col sums, atomics
    // D layout: row = 4*h + q, col = r  (HW-verified)
    #pragma unroll
    for (int m = 0; m < 4; ++m)
        #pragma unroll
        for (int n = 0; n < 4; ++n)
            #pragma unroll
            for (int q = 0; q < 4; ++q) {
                float v = expf(acc[m][n][q] * 10.0f);
                if (I == J && wr == wc && m == n && r == h * 4 + q) v = 0.f;
                acc[m][n][q] = v;
            }

    // row sums: rowsum[I*128 + wr*64 + m*16 + 4h+q] += sum over cols
    #pragma unroll
    for (int m = 0; m < 4; ++m) {
        float rs[4];
        #pragma unroll
        for (int q = 0; q < 4; ++q)
            rs[q] = acc[m][0][q] + acc[m][1][q] + acc[m][2][q] + acc[m][3][q];
        #pragma unroll
        for (int q = 0; q < 4; ++q)
            #pragma unroll
            for (int off = 1; off < 16; off <<= 1) rs[q] += __shfl_xor(rs[q], off);
        if (r == 0) {
            #pragma unroll
            for (int q = 0; q < 4; ++q)
                atomicAdd(&rowsum[I * TILE + wr * 64 + m * 16 + h * 4 + q], rs[q]);
        }
    }

    // col sums (S symmetric): rowsum[J*128 + wc*64 + n*16 + r] += sum over rows
    if (I != J) {
        #pragma unroll
        for (int n = 0; n < 4; ++n) {
            float cs = 0.f;
            #pragma unroll
            for (int m = 0; m < 4; ++m)
                #pragma unroll
                for (int q = 0; q < 4; ++q) cs += acc[m][n][q];
            cs += __shfl_xor(cs, 16);
            cs += __shfl_xor(cs, 32);
            if (lane < 16)
                atomicAdd(&rowsum[J * TILE + wc * 64 + n * 16 + r], cs);
        }
    }
}

// ---------------- Kernel 3: loss = mean(log(rowsum / (n-1))) ---------------
__global__ __launch_bounds__(256) void loss_kernel(
    const float* __restrict__ rowsum, float* __restrict__ out) {
    __shared__ float red[4];
    float s = 0.f;
    for (int i = threadIdx.x; i < N_CLS; i += 256)
        s += logf(rowsum[i] * (1.0f / (float)(N_CLS - 1)));
    #pragma unroll
    for (int off = 32; off; off >>= 1) s += __shfl_xor(s, off);
    if ((threadIdx.x & 63) == 0) red[threadIdx.x >> 6] = s;
    __syncthreads();
    if (threadIdx.x == 0)
        out[0] = (red[0] + red[1] + red[2] + red[3]) * (1.0f / (float)N_CLS);
}

extern "C" void kernel_launch(void* const* d_in, const int* in_sizes, int n_in,
                              void* d_out, int out_size, void* d_ws, size_t ws_size,
                              hipStream_t stream) {
    (void)in_sizes; (void)n_in; (void)out_size; (void)ws_size;
    const float* features = (const float*)d_in[0];
    const int*   labels   = (const int*)d_in[1];
    const float* protos   = (const float*)d_in[2];
    float* out = (float*)d_out;

    unsigned short* Phi = (unsigned short*)d_ws;                    // 8 MiB
    unsigned short* Plo = Phi + (size_t)N_CLS * FEAT;               // 8 MiB
    float* rowsum = (float*)(Plo + (size_t)N_CLS * FEAT);           // 32 KiB

    hipMemsetAsync(rowsum, 0, N_CLS * sizeof(float), stream);
    ema_split_kernel<<<N_CLS, 64, 0, stream>>>(features, labels, protos, Phi, Plo);
    gemm_disp_kernel<<<NBLK, 256, 0, stream>>>(Phi, Plo, rowsum);
    loss_kernel<<<1, 256, 0, stream>>>(rowsum, out);
}

// Round 2
// 125.870 us; speedup vs baseline: 1.4303x; 1.4303x over previous
//
#include <hip/hip_runtime.h>
#include <stdint.h>

#define N_CLS 8192
#define FEAT  512
#define BATCH 1024
#define TILE  128
#define BK    64
#define NTILE (N_CLS / TILE)               // 64
#define NBLK  (NTILE * (NTILE + 1) / 2)    // 2080

typedef __attribute__((ext_vector_type(8))) short short8;
typedef __attribute__((ext_vector_type(4))) float f32x4;

__device__ inline unsigned short f2bf(float x) {
    union { float f; unsigned int u; } v; v.f = x;
    unsigned int u = v.u;
    u += 0x7fffu + ((u >> 16) & 1u);       // RNE to bf16
    return (unsigned short)(u >> 16);
}

// ---------------- Kernel 1: sequential EMA per label -> bf16 protos --------
// One wave per class row; updates for a given class applied in batch order
// (matches lax.scan semantics; distinct classes independent). Also zeroes
// rowsum[row] so no separate memset dispatch is needed.
__global__ __launch_bounds__(256) void ema_kernel(
    const float* __restrict__ features, const int* __restrict__ labels,
    const float* __restrict__ protos,
    unsigned short* __restrict__ Phi, float* __restrict__ rowsum) {
    const int row  = blockIdx.x * 4 + (threadIdx.x >> 6);
    const int lane = threadIdx.x & 63;
    if (lane == 0) rowsum[row] = 0.f;

    float p[8];
    #pragma unroll
    for (int j = 0; j < 8; ++j) p[j] = protos[(size_t)row * FEAT + j * 64 + lane];

    for (int c = 0; c < BATCH / 64; ++c) {
        int lab = labels[c * 64 + lane];
        unsigned long long m = __ballot(lab == row);
        while (m) {
            int b = __builtin_ctzll(m);    // earliest remaining sample
            m &= m - 1;
            int s = c * 64 + b;
            float ss = 0.f;
            #pragma unroll
            for (int j = 0; j < 8; ++j) {
                float f = features[(size_t)s * FEAT + j * 64 + lane];
                p[j] = p[j] * 0.95f + f * 0.05f;
                ss += p[j] * p[j];
            }
            #pragma unroll
            for (int off = 32; off; off >>= 1) ss += __shfl_xor(ss, off);
            float inv = 1.0f / fmaxf(sqrtf(ss), 1e-12f);
            #pragma unroll
            for (int j = 0; j < 8; ++j) p[j] *= inv;
        }
    }
    #pragma unroll
    for (int j = 0; j < 8; ++j)
        Phi[(size_t)row * FEAT + j * 64 + lane] = f2bf(p[j]);
}

// ---------------- Kernel 2: symmetric Gram tiles + fused exp row/col sums --
// Single bf16 product; upper-triangular 128x128 tile pairs. BK=64, LDS
// XOR-swizzled (linear LDS dest + inverse-swizzled global source for
// global_load_lds; matching XOR on the ds_read side).
__global__ __launch_bounds__(256) void gemm_disp_kernel(
    const unsigned short* __restrict__ Phi, float* __restrict__ rowsum) {
    __shared__ short smem[2 * TILE * BK];  // A tile + B tile, 32 KiB

    // XCD-aware swizzle (NBLK = 2080 = 8*260, divisible -> simple form valid)
    int bid = blockIdx.x;
    int swz = (bid & 7) * (NBLK / 8) + (bid >> 3);
    int t = swz, I = 0;
    while (t >= NTILE - I) { t -= NTILE - I; ++I; }
    const int J = I + t;                   // J >= I

    const int wid  = threadIdx.x >> 6;     // 0..3
    const int lane = threadIdx.x & 63;
    const int wr = wid >> 1, wc = wid & 1; // 2x2 waves over 128x128
    const int h = lane >> 4;               // k-group 0..3
    const int r = lane & 15;               // fragment row/col

    f32x4 acc[4][4];
    #pragma unroll
    for (int m = 0; m < 4; ++m)
        #pragma unroll
        for (int n = 0; n < 4; ++n) acc[m][n] = (f32x4){0.f, 0.f, 0.f, 0.f};

    // staging: wave wid stages half of tile (wid>>1); 8 chunks x 1 KiB
    const int stile = wid >> 1;            // 0 = A rows (I), 1 = B rows (J)
    const int grow0 = (stile ? J : I) * TILE + (wid & 1) * 64;
    const int lrow0 = (wid & 1) * 64;      // row base within tile
    const int srow = lane >> 3;            // 0..7 within 8-row chunk
    const int sseg = (lane & 7) ^ srow;    // inverse-swizzled source segment

    for (int kk = 0; kk < FEAT; kk += BK) {
        #pragma unroll
        for (int c = 0; c < 8; ++c) {
            const unsigned short* gsrc =
                Phi + (size_t)(grow0 + c * 8 + srow) * FEAT + kk + sseg * 8;
            short* ldst = smem + stile * (TILE * BK) + (lrow0 + c * 8) * BK;
            __builtin_amdgcn_global_load_lds(
                (const __attribute__((address_space(1))) void*)gsrc,
                (__attribute__((address_space(3))) void*)ldst, 16, 0, 0);
        }
        __syncthreads();

        #pragma unroll
        for (int ksub = 0; ksub < 2; ++ksub) {
            short8 a[4], b[4];
            #pragma unroll
            for (int m = 0; m < 4; ++m) {
                int arow = wr * 64 + m * 16 + r;
                int brow = wc * 64 + m * 16 + r;
                int seg = (ksub * 4 + h) ^ (r & 7);   // read-side swizzle
                a[m] = *(const short8*)(smem + arow * BK + seg * 8);
                b[m] = *(const short8*)(smem + TILE * BK + brow * BK + seg * 8);
            }
            #pragma unroll
            for (int m = 0; m < 4; ++m)
                #pragma unroll
                for (int n = 0; n < 4; ++n)
                    acc[m][n] = __builtin_amdgcn_mfma_f32_16x16x32_bf16(
                        a[m], b[n], acc[m][n], 0, 0, 0);
        }
        __syncthreads();
    }

    // epilogue: e = exp(10*S), zero diagonal, reduce, atomics
    // D layout: row = 4*h + q, col = r (HW-verified)
    #pragma unroll
    for (int m = 0; m < 4; ++m)
        #pragma unroll
        for (int n = 0; n < 4; ++n)
            #pragma unroll
            for (int q = 0; q < 4; ++q) {
                float v = expf(acc[m][n][q] * 10.0f);
                if (I == J && wr == wc && m == n && r == h * 4 + q) v = 0.f;
                acc[m][n][q] = v;
            }

    // row sums -> rowsum[I*128 + wr*64 + m*16 + 4h+q]
    #pragma unroll
    for (int m = 0; m < 4; ++m) {
        float rs[4];
        #pragma unroll
        for (int q = 0; q < 4; ++q)
            rs[q] = acc[m][0][q] + acc[m][1][q] + acc[m][2][q] + acc[m][3][q];
        #pragma unroll
        for (int q = 0; q < 4; ++q)
            #pragma unroll
            for (int off = 1; off < 16; off <<= 1) rs[q] += __shfl_xor(rs[q], off);
        if (r == 0) {
            #pragma unroll
            for (int q = 0; q < 4; ++q)
                atomicAdd(&rowsum[I * TILE + wr * 64 + m * 16 + h * 4 + q], rs[q]);
        }
    }

    // col sums (symmetry) -> rowsum[J*128 + wc*64 + n*16 + r]
    if (I != J) {
        #pragma unroll
        for (int n = 0; n < 4; ++n) {
            float cs = 0.f;
            #pragma unroll
            for (int m = 0; m < 4; ++m)
                #pragma unroll
                for (int q = 0; q < 4; ++q) cs += acc[m][n][q];
            cs += __shfl_xor(cs, 16);
            cs += __shfl_xor(cs, 32);
            if (lane < 16)
                atomicAdd(&rowsum[J * TILE + wc * 64 + n * 16 + r], cs);
        }
    }
}

// ---------------- Kernel 3: loss = mean(log(rowsum / (n-1))) ---------------
__global__ __launch_bounds__(256) void loss_kernel(
    const float* __restrict__ rowsum, float* __restrict__ out) {
    __shared__ float red[4];
    float s = 0.f;
    for (int i = threadIdx.x; i < N_CLS; i += 256)
        s += logf(rowsum[i] * (1.0f / (float)(N_CLS - 1)));
    #pragma unroll
    for (int off = 32; off; off >>= 1) s += __shfl_xor(s, off);
    if ((threadIdx.x & 63) == 0) red[threadIdx.x >> 6] = s;
    __syncthreads();
    if (threadIdx.x == 0)
        out[0] = (red[0] + red[1] + red[2] + red[3]) * (1.0f / (float)N_CLS);
}

extern "C" void kernel_launch(void* const* d_in, const int* in_sizes, int n_in,
                              void* d_out, int out_size, void* d_ws, size_t ws_size,
                              hipStream_t stream) {
    (void)in_sizes; (void)n_in; (void)out_size; (void)ws_size;
    const float* features = (const float*)d_in[0];
    const int*   labels   = (const int*)d_in[1];
    const float* protos   = (const float*)d_in[2];
    float* out = (float*)d_out;

    unsigned short* Phi = (unsigned short*)d_ws;                    // 8 MiB
    float* rowsum = (float*)(Phi + (size_t)N_CLS * FEAT);           // 32 KiB

    ema_kernel<<<N_CLS / 4, 256, 0, stream>>>(features, labels, protos, Phi, rowsum);
    gemm_disp_kernel<<<NBLK, 256, 0, stream>>>(Phi, rowsum);
    loss_kernel<<<1, 256, 0, stream>>>(rowsum, out);
}

// Round 3
// 113.404 us; speedup vs baseline: 1.5875x; 1.1099x over previous
//
#include <hip/hip_runtime.h>
#include <stdint.h>

#define N_CLS 8192
#define FEAT  512
#define BATCH 1024
#define TILE  128
#define BK    64
#define NK    (FEAT / BK)                  // 8
#define NTILE (N_CLS / TILE)               // 64
#define NBLK  (NTILE * (NTILE + 1) / 2)    // 2080

typedef __attribute__((ext_vector_type(8))) short short8;
typedef __attribute__((ext_vector_type(4))) float f32x4;

__device__ inline unsigned short f2bf(float x) {
    union { float f; unsigned int u; } v; v.f = x;
    unsigned int u = v.u;
    u += 0x7fffu + ((u >> 16) & 1u);       // RNE to bf16
    return (unsigned short)(u >> 16);
}

// ---------------- Kernel 1: sequential EMA per label -> bf16 protos --------
__global__ __launch_bounds__(256) void ema_kernel(
    const float* __restrict__ features, const int* __restrict__ labels,
    const float* __restrict__ protos,
    unsigned short* __restrict__ Phi, float* __restrict__ rowsum) {
    const int row  = blockIdx.x * 4 + (threadIdx.x >> 6);
    const int lane = threadIdx.x & 63;
    if (lane == 0) rowsum[row] = 0.f;

    float p[8];
    #pragma unroll
    for (int j = 0; j < 8; ++j) p[j] = protos[(size_t)row * FEAT + j * 64 + lane];

    for (int c = 0; c < BATCH / 64; ++c) {
        int lab = labels[c * 64 + lane];
        unsigned long long m = __ballot(lab == row);
        while (m) {
            int b = __builtin_ctzll(m);    // earliest remaining sample
            m &= m - 1;
            int s = c * 64 + b;
            float ss = 0.f;
            #pragma unroll
            for (int j = 0; j < 8; ++j) {
                float f = features[(size_t)s * FEAT + j * 64 + lane];
                p[j] = p[j] * 0.95f + f * 0.05f;
                ss += p[j] * p[j];
            }
            #pragma unroll
            for (int off = 32; off; off >>= 1) ss += __shfl_xor(ss, off);
            float inv = 1.0f / fmaxf(sqrtf(ss), 1e-12f);
            #pragma unroll
            for (int j = 0; j < 8; ++j) p[j] *= inv;
        }
    }
    #pragma unroll
    for (int j = 0; j < 8; ++j)
        Phi[(size_t)row * FEAT + j * 64 + lane] = f2bf(p[j]);
}

// ---------------- Kernel 2: symmetric Gram tiles, 2-phase pipelined --------
// Double-buffered LDS; next K-tile staged (global_load_lds) before compute
// of current tile; single barrier per K-step (implicit vmcnt/lgkm drain).
__global__ __launch_bounds__(256) void gemm_disp_kernel(
    const unsigned short* __restrict__ Phi, float* __restrict__ rowsum) {
    __shared__ short smem[2 * 2 * TILE * BK];   // [buf][A|B][128][64], 64 KiB

    // XCD-aware swizzle (NBLK = 2080 divisible by 8)
    int bid = blockIdx.x;
    int swz = (bid & 7) * (NBLK / 8) + (bid >> 3);
    int t = swz, I = 0;
    while (t >= NTILE - I) { t -= NTILE - I; ++I; }
    const int J = I + t;                   // J >= I

    const int wid  = threadIdx.x >> 6;     // 0..3
    const int lane = threadIdx.x & 63;
    const int wr = wid >> 1, wc = wid & 1; // 2x2 waves over 128x128
    const int h = lane >> 4;               // k-group 0..3
    const int r = lane & 15;               // fragment row/col

    f32x4 acc[4][4];
    #pragma unroll
    for (int m = 0; m < 4; ++m)
        #pragma unroll
        for (int n = 0; n < 4; ++n) acc[m][n] = (f32x4){0.f, 0.f, 0.f, 0.f};

    // staging geometry: wave wid stages half of tile (wid>>1); 8 x 1 KiB
    const int stile = wid >> 1;            // 0 = A rows (I), 1 = B rows (J)
    const int grow0 = (stile ? J : I) * TILE + (wid & 1) * 64;
    const int lrow0 = (wid & 1) * 64;
    const int srow = lane >> 3;            // 0..7 within 8-row chunk
    const int sseg = (lane & 7) ^ srow;    // inverse-swizzled source segment
    const unsigned short* gbase =
        Phi + (size_t)grow0 * FEAT + (size_t)srow * FEAT + sseg * 8;

#define STAGE(buf, kk)                                                        \
    {                                                                         \
        _Pragma("unroll")                                                     \
        for (int c = 0; c < 8; ++c) {                                         \
            const unsigned short* gsrc = gbase + (size_t)(c * 8) * FEAT + (kk); \
            short* ldst = smem + (buf) * (2 * TILE * BK)                      \
                        + stile * (TILE * BK) + (lrow0 + c * 8) * BK;         \
            __builtin_amdgcn_global_load_lds(                                 \
                (const __attribute__((address_space(1))) void*)gsrc,          \
                (__attribute__((address_space(3))) void*)ldst, 16, 0, 0);     \
        }                                                                     \
    }

    STAGE(0, 0);
    __syncthreads();

    for (int kt = 0; kt < NK; ++kt) {
        const int cur = kt & 1;
        if (kt + 1 < NK) STAGE(cur ^ 1, (kt + 1) * BK);

        const short* abase = smem + cur * (2 * TILE * BK);
        const short* bbase = abase + TILE * BK;
        #pragma unroll
        for (int ksub = 0; ksub < 2; ++ksub) {
            short8 a[4], b[4];
            const int seg = (ksub * 4 + h) ^ (r & 7);   // read-side swizzle
            #pragma unroll
            for (int m = 0; m < 4; ++m) {
                int arow = wr * 64 + m * 16 + r;
                int brow = wc * 64 + m * 16 + r;
                a[m] = *(const short8*)(abase + arow * BK + seg * 8);
                b[m] = *(const short8*)(bbase + brow * BK + seg * 8);
            }
            #pragma unroll
            for (int m = 0; m < 4; ++m)
                #pragma unroll
                for (int n = 0; n < 4; ++n)
                    acc[m][n] = __builtin_amdgcn_mfma_f32_16x16x32_bf16(
                        a[m], b[n], acc[m][n], 0, 0, 0);
        }
        __syncthreads();   // implicit vmcnt(0)+lgkmcnt(0): next tile staged,
                           // all waves done reading buf[cur]
    }

    // epilogue: e = exp(10*S), zero diagonal, reduce, atomics
    // D layout: row = 4*h + q, col = r (HW-verified)
    #pragma unroll
    for (int m = 0; m < 4; ++m)
        #pragma unroll
        for (int n = 0; n < 4; ++n)
            #pragma unroll
            for (int q = 0; q < 4; ++q) {
                float v = expf(acc[m][n][q] * 10.0f);
                if (I == J && wr == wc && m == n && r == h * 4 + q) v = 0.f;
                acc[m][n][q] = v;
            }

    // row sums -> rowsum[I*128 + wr*64 + m*16 + 4h+q]
    #pragma unroll
    for (int m = 0; m < 4; ++m) {
        float rs[4];
        #pragma unroll
        for (int q = 0; q < 4; ++q)
            rs[q] = acc[m][0][q] + acc[m][1][q] + acc[m][2][q] + acc[m][3][q];
        #pragma unroll
        for (int q = 0; q < 4; ++q)
            #pragma unroll
            for (int off = 1; off < 16; off <<= 1) rs[q] += __shfl_xor(rs[q], off);
        if (r == 0) {
            #pragma unroll
            for (int q = 0; q < 4; ++q)
                atomicAdd(&rowsum[I * TILE + wr * 64 + m * 16 + h * 4 + q], rs[q]);
        }
    }

    // col sums (symmetry) -> rowsum[J*128 + wc*64 + n*16 + r]
    if (I != J) {
        #pragma unroll
        for (int n = 0; n < 4; ++n) {
            float cs = 0.f;
            #pragma unroll
            for (int m = 0; m < 4; ++m)
                #pragma unroll
                for (int q = 0; q < 4; ++q) cs += acc[m][n][q];
            cs += __shfl_xor(cs, 16);
            cs += __shfl_xor(cs, 32);
            if (lane < 16)
                atomicAdd(&rowsum[J * TILE + wc * 64 + n * 16 + r], cs);
        }
    }
}

// ---------------- Kernel 3: loss = mean(log(rowsum / (n-1))) ---------------
__global__ __launch_bounds__(256) void loss_kernel(
    const float* __restrict__ rowsum, float* __restrict__ out) {
    __shared__ float red[4];
    float s = 0.f;
    for (int i = threadIdx.x; i < N_CLS; i += 256)
        s += logf(rowsum[i] * (1.0f / (float)(N_CLS - 1)));
    #pragma unroll
    for (int off = 32; off; off >>= 1) s += __shfl_xor(s, off);
    if ((threadIdx.x & 63) == 0) red[threadIdx.x >> 6] = s;
    __syncthreads();
    if (threadIdx.x == 0)
        out[0] = (red[0] + red[1] + red[2] + red[3]) * (1.0f / (float)N_CLS);
}

extern "C" void kernel_launch(void* const* d_in, const int* in_sizes, int n_in,
                              void* d_out, int out_size, void* d_ws, size_t ws_size,
                              hipStream_t stream) {
    (void)in_sizes; (void)n_in; (void)out_size; (void)ws_size;
    const float* features = (const float*)d_in[0];
    const int*   labels   = (const int*)d_in[1];
    const float* protos   = (const float*)d_in[2];
    float* out = (float*)d_out;

    unsigned short* Phi = (unsigned short*)d_ws;                    // 8 MiB
    float* rowsum = (float*)(Phi + (size_t)N_CLS * FEAT);           // 32 KiB

    ema_kernel<<<N_CLS / 4, 256, 0, stream>>>(features, labels, protos, Phi, rowsum);
    gemm_disp_kernel<<<NBLK, 256, 0, stream>>>(Phi, rowsum);
    loss_kernel<<<1, 256, 0, stream>>>(rowsum, out);
}

// Round 4
// 99.795 us; speedup vs baseline: 1.8040x; 1.1364x over previous
//
#include <hip/hip_runtime.h>
#include <stdint.h>

#define N_CLS 8192
#define FEAT  512
#define BATCH 1024
#define TILE  256
#define BK    64
#define NK    (FEAT / BK)                  // 8
#define NTILE (N_CLS / TILE)               // 32
#define NBLK  (NTILE * (NTILE + 1) / 2)    // 528
#define BUFSH (2 * TILE * BK)              // shorts per buffer (A+B): 32768 = 64 KiB

typedef __attribute__((ext_vector_type(8))) short short8;
typedef __attribute__((ext_vector_type(4))) float f32x4;

__device__ inline unsigned short f2bf(float x) {
    union { float f; unsigned int u; } v; v.f = x;
    unsigned int u = v.u;
    u += 0x7fffu + ((u >> 16) & 1u);       // RNE to bf16
    return (unsigned short)(u >> 16);
}

// ---------------- Kernel 1: sequential EMA per label -> bf16 protos --------
__global__ __launch_bounds__(256) void ema_kernel(
    const float* __restrict__ features, const int* __restrict__ labels,
    const float* __restrict__ protos,
    unsigned short* __restrict__ Phi, float* __restrict__ rowsum) {
    const int row  = blockIdx.x * 4 + (threadIdx.x >> 6);
    const int lane = threadIdx.x & 63;
    if (lane == 0) rowsum[row] = 0.f;

    float p[8];
    #pragma unroll
    for (int j = 0; j < 8; ++j) p[j] = protos[(size_t)row * FEAT + j * 64 + lane];

    for (int c = 0; c < BATCH / 64; ++c) {
        int lab = labels[c * 64 + lane];
        unsigned long long m = __ballot(lab == row);
        while (m) {
            int b = __builtin_ctzll(m);    // earliest remaining sample
            m &= m - 1;
            int s = c * 64 + b;
            float ss = 0.f;
            #pragma unroll
            for (int j = 0; j < 8; ++j) {
                float f = features[(size_t)s * FEAT + j * 64 + lane];
                p[j] = p[j] * 0.95f + f * 0.05f;
                ss += p[j] * p[j];
            }
            #pragma unroll
            for (int off = 32; off; off >>= 1) ss += __shfl_xor(ss, off);
            float inv = 1.0f / fmaxf(sqrtf(ss), 1e-12f);
            #pragma unroll
            for (int j = 0; j < 8; ++j) p[j] *= inv;
        }
    }
    #pragma unroll
    for (int j = 0; j < 8; ++j)
        Phi[(size_t)row * FEAT + j * 64 + lane] = f2bf(p[j]);
}

// ---------------- Kernel 2: 256^2 symmetric Gram tiles, 8 waves ------------
// Wave-tile 128x64 (384 B/MFMA -> under LDS b128 ceiling). Double-buffered
// 128 KiB LDS; all staging for tile t+1 issued in phase 0 of tile t; one
// __syncthreads per K-tile (its vmcnt(0) gates exactly the 8 loads issued
// one full K-tile earlier). XOR-swizzled LDS (proven 0-conflict in R2/R3).
__global__ __launch_bounds__(512, 2) void gemm_disp_kernel(
    const unsigned short* __restrict__ Phi, float* __restrict__ rowsum) {
    __shared__ short smem[2 * BUFSH];      // 128 KiB

    // XCD-aware swizzle (528 = 8*66, divisible -> simple form bijective)
    int bid = blockIdx.x;
    int swz = (bid & 7) * (NBLK / 8) + (bid >> 3);
    int t = swz, I = 0;
    while (t >= NTILE - I) { t -= NTILE - I; ++I; }
    const int J = I + t;                   // J >= I

    const int w    = threadIdx.x >> 6;     // wave 0..7
    const int lane = threadIdx.x & 63;
    const int wr = w >> 2, wc = w & 3;     // 2x4 waves, 128x64 output each
    const int h = lane >> 4;               // k-group 0..3
    const int r = lane & 15;               // fragment row/col

    const int Ibase = I * TILE, Jbase = J * TILE;

    f32x4 acc[8][4];
    #pragma unroll
    for (int m = 0; m < 8; ++m)
        #pragma unroll
        for (int n = 0; n < 4; ++n) acc[m][n] = (f32x4){0.f, 0.f, 0.f, 0.f};

    // staging: wave w stages 4 chunks of A (rows of I-tile) + 4 of B (J-tile)
    const int srow = lane >> 3;            // 0..7 within 8-row chunk
    const int sseg = (lane & 7) ^ srow;    // inverse-swizzled source segment

#define STAGE(buf, kk)                                                        \
    {                                                                         \
        _Pragma("unroll")                                                     \
        for (int i = 0; i < 4; ++i) {                                         \
            const int rr = (w * 4 + i) * 8 + srow;                            \
            const unsigned short* ga =                                        \
                Phi + (size_t)(Ibase + rr) * FEAT + (kk) + sseg * 8;          \
            const unsigned short* gb =                                        \
                Phi + (size_t)(Jbase + rr) * FEAT + (kk) + sseg * 8;          \
            short* la = smem + (buf) * BUFSH + (w * 4 + i) * 512;             \
            short* lb = la + TILE * BK;                                       \
            __builtin_amdgcn_global_load_lds(                                 \
                (const __attribute__((address_space(1))) void*)ga,            \
                (__attribute__((address_space(3))) void*)la, 16, 0, 0);       \
            __builtin_amdgcn_global_load_lds(                                 \
                (const __attribute__((address_space(1))) void*)gb,            \
                (__attribute__((address_space(3))) void*)lb, 16, 0, 0);       \
        }                                                                     \
    }

    STAGE(0, 0);

    for (int kt = 0; kt < NK; ++kt) {
        const int cur = kt & 1;
        __syncthreads();   // vmcnt(0): tile kt's loads (issued 1 K-tile ago)
                           // landed; all waves done reading buf[cur^1]
        const short* As = smem + cur * BUFSH;
        const short* Bs = As + TILE * BK;
        const int s0 = h ^ (r & 7);            // ksub=0 swizzled segment
        const int s1 = (4 + h) ^ (r & 7);      // ksub=1
        short8 a[4], b[4];

        // ---- phase 0: quadrant (mh=0, ks=0) + issue ALL next-tile staging
        #pragma unroll
        for (int n = 0; n < 4; ++n)
            b[n] = *(const short8*)(Bs + (wc * 64 + n * 16 + r) * BK + s0 * 8);
        #pragma unroll
        for (int i = 0; i < 4; ++i)
            a[i] = *(const short8*)(As + (wr * 128 + i * 16 + r) * BK + s0 * 8);
        if (kt + 1 < NK) STAGE(cur ^ 1, (kt + 1) * BK);
        __builtin_amdgcn_s_setprio(1);
        #pragma unroll
        for (int i = 0; i < 4; ++i)
            #pragma unroll
            for (int n = 0; n < 4; ++n)
                acc[i][n] = __builtin_amdgcn_mfma_f32_16x16x32_bf16(
                    a[i], b[n], acc[i][n], 0, 0, 0);
        __builtin_amdgcn_s_setprio(0);

        // ---- phase 1: quadrant (mh=1, ks=0)
        #pragma unroll
        for (int i = 0; i < 4; ++i)
            a[i] = *(const short8*)(As + (wr * 128 + 64 + i * 16 + r) * BK + s0 * 8);
        __builtin_amdgcn_s_setprio(1);
        #pragma unroll
        for (int i = 0; i < 4; ++i)
            #pragma unroll
            for (int n = 0; n < 4; ++n)
                acc[4 + i][n] = __builtin_amdgcn_mfma_f32_16x16x32_bf16(
                    a[i], b[n], acc[4 + i][n], 0, 0, 0);
        __builtin_amdgcn_s_setprio(0);

        // ---- phase 2: quadrant (mh=0, ks=1)
        #pragma unroll
        for (int n = 0; n < 4; ++n)
            b[n] = *(const short8*)(Bs + (wc * 64 + n * 16 + r) * BK + s1 * 8);
        #pragma unroll
        for (int i = 0; i < 4; ++i)
            a[i] = *(const short8*)(As + (wr * 128 + i * 16 + r) * BK + s1 * 8);
        __builtin_amdgcn_s_setprio(1);
        #pragma unroll
        for (int i = 0; i < 4; ++i)
            #pragma unroll
            for (int n = 0; n < 4; ++n)
                acc[i][n] = __builtin_amdgcn_mfma_f32_16x16x32_bf16(
                    a[i], b[n], acc[i][n], 0, 0, 0);
        __builtin_amdgcn_s_setprio(0);

        // ---- phase 3: quadrant (mh=1, ks=1)
        #pragma unroll
        for (int i = 0; i < 4; ++i)
            a[i] = *(const short8*)(As + (wr * 128 + 64 + i * 16 + r) * BK + s1 * 8);
        __builtin_amdgcn_s_setprio(1);
        #pragma unroll
        for (int i = 0; i < 4; ++i)
            #pragma unroll
            for (int n = 0; n < 4; ++n)
                acc[4 + i][n] = __builtin_amdgcn_mfma_f32_16x16x32_bf16(
                    a[i], b[n], acc[4 + i][n], 0, 0, 0);
        __builtin_amdgcn_s_setprio(0);
    }

    // epilogue: e = exp(10*S), zero diagonal, reduce, atomics
    // D layout: row = 4*h + q, col = r (HW-verified)
    #pragma unroll
    for (int m = 0; m < 8; ++m)
        #pragma unroll
        for (int n = 0; n < 4; ++n)
            #pragma unroll
            for (int q = 0; q < 4; ++q) {
                float v = __expf(acc[m][n][q] * 10.0f);
                if (I == J &&
                    (wr * 128 + m * 16 + h * 4 + q) == (wc * 64 + n * 16 + r))
                    v = 0.f;
                acc[m][n][q] = v;
            }

    // row sums -> rowsum[Ibase + wr*128 + m*16 + 4h+q]
    #pragma unroll
    for (int m = 0; m < 8; ++m) {
        float rs[4];
        #pragma unroll
        for (int q = 0; q < 4; ++q)
            rs[q] = acc[m][0][q] + acc[m][1][q] + acc[m][2][q] + acc[m][3][q];
        #pragma unroll
        for (int q = 0; q < 4; ++q)
            #pragma unroll
            for (int off = 1; off < 16; off <<= 1) rs[q] += __shfl_xor(rs[q], off);
        if (r == 0) {
            #pragma unroll
            for (int q = 0; q < 4; ++q)
                atomicAdd(&rowsum[Ibase + wr * 128 + m * 16 + h * 4 + q], rs[q]);
        }
    }

    // col sums (symmetry) -> rowsum[Jbase + wc*64 + n*16 + r]
    if (I != J) {
        #pragma unroll
        for (int n = 0; n < 4; ++n) {
            float cs = 0.f;
            #pragma unroll
            for (int m = 0; m < 8; ++m)
                #pragma unroll
                for (int q = 0; q < 4; ++q) cs += acc[m][n][q];
            cs += __shfl_xor(cs, 16);
            cs += __shfl_xor(cs, 32);
            if (lane < 16)
                atomicAdd(&rowsum[Jbase + wc * 64 + n * 16 + r], cs);
        }
    }
}

// ---------------- Kernel 3: loss = mean(log(rowsum / (n-1))) ---------------
__global__ __launch_bounds__(512) void loss_kernel(
    const float* __restrict__ rowsum, float* __restrict__ out) {
    __shared__ float red[8];
    float s = 0.f;
    for (int i = threadIdx.x; i < N_CLS; i += 512)
        s += logf(rowsum[i] * (1.0f / (float)(N_CLS - 1)));
    #pragma unroll
    for (int off = 32; off; off >>= 1) s += __shfl_xor(s, off);
    if ((threadIdx.x & 63) == 0) red[threadIdx.x >> 6] = s;
    __syncthreads();
    if (threadIdx.x == 0) {
        float tot = 0.f;
        #pragma unroll
        for (int i = 0; i < 8; ++i) tot += red[i];
        out[0] = tot * (1.0f / (float)N_CLS);
    }
}

extern "C" void kernel_launch(void* const* d_in, const int* in_sizes, int n_in,
                              void* d_out, int out_size, void* d_ws, size_t ws_size,
                              hipStream_t stream) {
    (void)in_sizes; (void)n_in; (void)out_size; (void)ws_size;
    const float* features = (const float*)d_in[0];
    const int*   labels   = (const int*)d_in[1];
    const float* protos   = (const float*)d_in[2];
    float* out = (float*)d_out;

    unsigned short* Phi = (unsigned short*)d_ws;                    // 8 MiB
    float* rowsum = (float*)(Phi + (size_t)N_CLS * FEAT);           // 32 KiB

    ema_kernel<<<N_CLS / 4, 256, 0, stream>>>(features, labels, protos, Phi, rowsum);
    gemm_disp_kernel<<<NBLK, 512, 0, stream>>>(Phi, rowsum);
    loss_kernel<<<1, 512, 0, stream>>>(rowsum, out);
}